// Round 3
// baseline (84.361 us; speedup 1.0000x reference)
//
#include <hip/hip_runtime.h>

#define T_STEPS 2048
#define NI 4096
#define NO 4096

static constexpr float BETA = 0.9f;
static constexpr float THRESH = 1.0f;

#define SPK_FLOATS ((unsigned)T_STEPS * (unsigned)NO)      // 8,388,608
#define OUT_FLOATS (2u * SPK_FLOATS)                       // 16,777,216
#define SPK_VEC4   (SPK_FLOATS / 4u)                       // 2,097,152
#define TOT_VEC4   (OUT_FLOATS / 4u)                       // 4,194,304

// Workspace layout in d_ws
struct Ws {
  int tstar;                 // global first spike step (min over neurons)
  int pad;
  unsigned long long packed; // winner key: ((noise_bits>>9) << 32) | (NO-1-o)
  float cur0[NO];            // cur at t=0 (for general-path restart)
  int fst[NO];               // per-neuron first spike step (T_STEPS if none)
};

// ---- Threefry-2x32, key = (0, 42), matching JAX's threefry2x32 ----
__device__ inline void threefry2x32(unsigned k0, unsigned k1,
                                    unsigned& x0, unsigned& x1) {
  const unsigned k2 = k0 ^ k1 ^ 0x1BD11BDAu;
  x0 += k0; x1 += k1;
#define TF_RND(r) { x0 += x1; x1 = (x1 << (r)) | (x1 >> (32 - (r))); x1 ^= x0; }
  TF_RND(13) TF_RND(15) TF_RND(26) TF_RND(6)
  x0 += k1; x1 += k2 + 1u;
  TF_RND(17) TF_RND(29) TF_RND(16) TF_RND(24)
  x0 += k2; x1 += k0 + 2u;
  TF_RND(13) TF_RND(15) TF_RND(26) TF_RND(6)
  x0 += k0; x1 += k1 + 3u;
  TF_RND(17) TF_RND(29) TF_RND(16) TF_RND(24)
  x0 += k1; x1 += k2 + 4u;
  TF_RND(13) TF_RND(15) TF_RND(26) TF_RND(6)
  x0 += k2; x1 += k0 + 5u;
#undef TF_RND
}

// Winner key for neuron o spiking at step ts (noise row ts, monotone in the
// uniform float; ties broken toward smaller o).
__device__ inline unsigned long long winner_key(int ts, int o) {
  const unsigned H = (unsigned)T_STEPS * (unsigned)NO / 2u; // 4194304
  const unsigned i = (unsigned)ts * (unsigned)NO + (unsigned)o;
  unsigned c0 = (i < H) ? i : (i - H);
  unsigned c1 = (i < H) ? (i + H) : i;
  threefry2x32(0u, 42u, c0, c1);
  const unsigned bits = (i < H) ? c0 : c1;
  const unsigned mant = bits >> 9;
  return ((unsigned long long)mant << 32) | (unsigned)(NO - 1 - o);
}

__global__ void k_init(Ws* ws) {
  ws->tstar = T_STEPS;
  ws->packed = 0ull;
}

// One wave per neuron: cur0[o] = x[0]·W[o]. Writes mem_rec row 0 (always
// recorded — done starts False). Neurons with cur0 > threshold are t=0
// spikers: fst=0, tstar→0, and they enter the winner race directly (valid
// because t=0 candidates exist iff tstar==0).
__global__ __launch_bounds__(256) void k_gemv0(const float* __restrict__ x,
                                               const float* __restrict__ W,
                                               float* __restrict__ mem_rec,
                                               Ws* __restrict__ ws) {
  const int wid  = (int)((blockIdx.x * blockDim.x + threadIdx.x) >> 6);
  const int lane = (int)(threadIdx.x & 63);
  if (wid >= NO) return;

  const float4* Wrow = reinterpret_cast<const float4*>(W) + (size_t)wid * (NI / 4);
  const float4* xr   = reinterpret_cast<const float4*>(x); // row 0

  float acc = 0.0f;
#pragma unroll
  for (int j = 0; j < 16; ++j) {
    float4 wv = Wrow[j * 64 + lane];
    float4 xv = xr[j * 64 + lane];
    acc += xv.x * wv.x;
    acc += xv.y * wv.y;
    acc += xv.z * wv.z;
    acc += xv.w * wv.w;
  }
#pragma unroll
  for (int off = 32; off >= 1; off >>= 1) acc += __shfl_xor(acc, off, 64);

  if (lane == 0) {
    mem_rec[wid] = acc;       // row 0
    ws->cur0[wid] = acc;
    if (acc > THRESH) {
      ws->fst[wid] = 0;
      atomicMin(&ws->tstar, 0);
      atomicMax(&ws->packed, winner_key(0, wid));
    } else {
      ws->fst[wid] = T_STEPS;
    }
  }
}

// General-path fallback: only runs if NO neuron spiked at t=0 (never for the
// benchmark input — exits immediately). One wave per neuron, simulate from
// t=1 until own first spike, writing mem rows as it goes. Rows past the
// global tstar are zeroed later by k_out.
__global__ __launch_bounds__(256) void k_slow(const float* __restrict__ x,
                                              const float* __restrict__ W,
                                              float* __restrict__ mem_rec,
                                              Ws* __restrict__ ws) {
  if (ws->tstar == 0) return;

  const int wid  = (int)((blockIdx.x * blockDim.x + threadIdx.x) >> 6);
  const int lane = (int)(threadIdx.x & 63);
  if (wid >= NO) return;

  const float4* Wrow = reinterpret_cast<const float4*>(W) + (size_t)wid * (NI / 4);
  float4 w[16];
#pragma unroll
  for (int j = 0; j < 16; ++j) w[j] = Wrow[j * 64 + lane];

  float mem = ws->cur0[wid];
  int my_fst = T_STEPS;

  for (int t = 1; t < T_STEPS; ++t) {
    const float4* xr = reinterpret_cast<const float4*>(x) + (size_t)t * (NI / 4);
    float acc = 0.0f;
#pragma unroll
    for (int j = 0; j < 16; ++j) {
      float4 xv = xr[j * 64 + lane];
      acc += xv.x * w[j].x;
      acc += xv.y * w[j].y;
      acc += xv.z * w[j].z;
      acc += xv.w * w[j].w;
    }
#pragma unroll
    for (int off = 32; off >= 1; off >>= 1) acc += __shfl_xor(acc, off, 64);

    const float reset = (mem > THRESH) ? THRESH : 0.0f;
    mem = BETA * mem + acc - reset;

    if (lane == 0) mem_rec[(size_t)t * NO + wid] = mem;
    if (mem > THRESH) { my_fst = t; break; }
  }

  if (lane == 0) {
    ws->fst[wid] = my_fst;
    atomicMin(&ws->tstar, my_fst);
  }
}

// General-path winner candidates (fst[o] == tstar > 0). Fast path exits.
__global__ void k_fix(Ws* __restrict__ ws) {
  const int ts = ws->tstar;
  if (ts == 0 || ts >= T_STEPS) return;
  const int o = blockIdx.x * blockDim.x + threadIdx.x;
  if (o >= NO) return;
  if (ws->fst[o] == ts) atomicMax(&ws->packed, winner_key(ts, o));
}

// Epilogue fill: writes the entire spk region (zeros + winner one-hot) and
// zeroes mem rows t > tstar. Skips mem row 0 (k_gemv0 wrote it) and rows
// 1..tstar (general path: k_slow wrote them).
__global__ __launch_bounds__(256) void k_out(float4* __restrict__ out,
                                             const Ws* __restrict__ ws) {
  const unsigned tid    = blockIdx.x * blockDim.x + threadIdx.x;
  const unsigned stride = gridDim.x * blockDim.x;
  const int ts = ws->tstar;

  unsigned wflat = 0xFFFFFFFFu; // flat float index of the winner in spk
  if (ts < T_STEPS) {
    const unsigned o =
        (unsigned)(NO - 1) - (unsigned)(ws->packed & 0xFFFFFFFFull);
    wflat = (unsigned)ts * (unsigned)NO + o;
  }

  const float4 z = {0.0f, 0.0f, 0.0f, 0.0f};
  for (unsigned v = tid; v < TOT_VEC4; v += stride) {
    if (v < SPK_VEC4) {
      float4 val = z;
      const unsigned d = wflat - v * 4u; // unsigned wrap: only 0..3 hit
      if (d < 4u) reinterpret_cast<float*>(&val)[d] = 1.0f;
      out[v] = val;
    } else {
      const unsigned t = (v - SPK_VEC4) >> 10; // NO/4 = 1024 float4 per row
      if ((int)t > ts) out[v] = z;             // rows <= tstar already written
    }
  }
}

extern "C" void kernel_launch(void* const* d_in, const int* in_sizes, int n_in,
                              void* d_out, int out_size, void* d_ws, size_t ws_size,
                              hipStream_t stream) {
  const float* x = (const float*)d_in[0]; // [T, NI]
  const float* W = (const float*)d_in[1]; // [NO, NI]
  float* mem = (float*)d_out + (size_t)T_STEPS * NO;   // output 1: [T, NO]
  Ws* ws = (Ws*)d_ws;

  k_init<<<1, 1, 0, stream>>>(ws);
  k_gemv0<<<(NO * 64) / 256, 256, 0, stream>>>(x, W, mem, ws);
  k_slow<<<(NO * 64) / 256, 256, 0, stream>>>(x, W, mem, ws);
  k_fix<<<NO / 256, 256, 0, stream>>>(ws);
  k_out<<<4096, 256, 0, stream>>>((float4*)d_out, ws);
}

// Round 4
// 54.324 us; speedup vs baseline: 1.5529x; 1.5529x over previous
//
#include <hip/hip_runtime.h>

#define T_STEPS 2048
#define NI 4096
#define NO 4096

static constexpr float BETA = 0.9f;
static constexpr float THRESH = 1.0f;

#define SPK_FLOATS ((unsigned)T_STEPS * (unsigned)NO)      // 8,388,608
#define OUT_FLOATS (2u * SPK_FLOATS)                       // 16,777,216
#define SPK_VEC4   (SPK_FLOATS / 4u)                       // 2,097,152
#define TOT_VEC4   (OUT_FLOATS / 4u)                       // 4,194,304

// Workspace layout in d_ws
struct Ws {
  int tstar;                 // global first spike step
  int pad;
  unsigned long long packed; // winner key (bit63 | mant<<32 | (NO-1-o))
  float cur0[NO];            // cur at t=0 (general-path restart)
  int fst[NO];               // per-neuron first spike step (general path)
  unsigned long long key0[NO]; // t=0 winner keys (0 = not a spiker)
};

// ---- Threefry-2x32, key = (0, 42), matching JAX's threefry2x32 ----
__device__ inline void threefry2x32(unsigned k0, unsigned k1,
                                    unsigned& x0, unsigned& x1) {
  const unsigned k2 = k0 ^ k1 ^ 0x1BD11BDAu;
  x0 += k0; x1 += k1;
#define TF_RND(r) { x0 += x1; x1 = (x1 << (r)) | (x1 >> (32 - (r))); x1 ^= x0; }
  TF_RND(13) TF_RND(15) TF_RND(26) TF_RND(6)
  x0 += k1; x1 += k2 + 1u;
  TF_RND(17) TF_RND(29) TF_RND(16) TF_RND(24)
  x0 += k2; x1 += k0 + 2u;
  TF_RND(13) TF_RND(15) TF_RND(26) TF_RND(6)
  x0 += k0; x1 += k1 + 3u;
  TF_RND(17) TF_RND(29) TF_RND(16) TF_RND(24)
  x0 += k1; x1 += k2 + 4u;
  TF_RND(13) TF_RND(15) TF_RND(26) TF_RND(6)
  x0 += k2; x1 += k0 + 5u;
#undef TF_RND
}

// Winner key for neuron o spiking at step ts. Bit 63 marks "is a candidate"
// (guarantees nonzero); mant is monotone in the uniform float; low word
// breaks ties toward smaller o (matching argmax first-index).
__device__ inline unsigned long long winner_key(int ts, int o) {
  const unsigned H = (unsigned)T_STEPS * (unsigned)NO / 2u; // 4194304
  const unsigned i = (unsigned)ts * (unsigned)NO + (unsigned)o;
  unsigned c0 = (i < H) ? i : (i - H);
  unsigned c1 = (i < H) ? (i + H) : i;
  threefry2x32(0u, 42u, c0, c1);
  const unsigned bits = (i < H) ? c0 : c1;
  const unsigned mant = bits >> 9;
  return (1ull << 63) | ((unsigned long long)mant << 32) |
         (unsigned)(NO - 1 - o);
}

// Block-per-neuron: cur0[o] = x[0]·W[o]. Writes mem_rec row 0 (always
// recorded — done starts False) and the per-neuron winner key. NO atomics.
__global__ __launch_bounds__(256) void k_gemv0(const float* __restrict__ x,
                                               const float* __restrict__ W,
                                               float* __restrict__ mem_rec,
                                               Ws* __restrict__ ws) {
  const int o   = (int)blockIdx.x;
  const int tid = (int)threadIdx.x;

  const float4* Wrow = reinterpret_cast<const float4*>(W) + (size_t)o * (NI / 4);
  const float4* xr   = reinterpret_cast<const float4*>(x); // row 0

  float acc = 0.0f;
#pragma unroll
  for (int k = 0; k < 4; ++k) {
    const int idx = tid + k * 256;
    float4 wv = Wrow[idx];
    float4 xv = xr[idx];
    acc += wv.x * xv.x + wv.y * xv.y + wv.z * xv.z + wv.w * xv.w;
  }
#pragma unroll
  for (int off = 32; off >= 1; off >>= 1) acc += __shfl_xor(acc, off, 64);

  __shared__ float part[4];
  if ((tid & 63) == 0) part[tid >> 6] = acc;
  __syncthreads();
  if (tid == 0) {
    const float cur = part[0] + part[1] + part[2] + part[3];
    mem_rec[o]   = cur;   // row 0
    ws->cur0[o]  = cur;
    ws->key0[o]  = (cur > THRESH) ? winner_key(0, o) : 0ull;
  }
}

// Single-block max-reduce over key0: sets tstar (0 if any t=0 spiker, else
// T_STEPS) and packed. No atomics anywhere on the fast path.
__global__ __launch_bounds__(1024) void k_reduce0(Ws* __restrict__ ws) {
  const int tid = (int)threadIdx.x;
  unsigned long long k = 0ull;
#pragma unroll
  for (int j = 0; j < NO / 1024; ++j) {
    const unsigned long long v = ws->key0[tid + j * 1024];
    k = (v > k) ? v : k;
  }
#pragma unroll
  for (int off = 32; off >= 1; off >>= 1) {
    const unsigned long long v = __shfl_xor(k, off, 64);
    k = (v > k) ? v : k;
  }
  __shared__ unsigned long long part[16];
  if ((tid & 63) == 0) part[tid >> 6] = k;
  __syncthreads();
  if (tid == 0) {
    unsigned long long m = 0ull;
#pragma unroll
    for (int j = 0; j < 16; ++j) m = (part[j] > m) ? part[j] : m;
    ws->packed = m;
    ws->tstar  = (m != 0ull) ? 0 : T_STEPS;
  }
}

// General-path fallback: only runs if NO neuron spiked at t=0 (never for the
// benchmark input — exits immediately). One wave per neuron from t=1.
__global__ __launch_bounds__(256) void k_slow(const float* __restrict__ x,
                                              const float* __restrict__ W,
                                              float* __restrict__ mem_rec,
                                              Ws* __restrict__ ws) {
  if (ws->tstar == 0) return;

  const int wid  = (int)((blockIdx.x * blockDim.x + threadIdx.x) >> 6);
  const int lane = (int)(threadIdx.x & 63);
  if (wid >= NO) return;

  const float4* Wrow = reinterpret_cast<const float4*>(W) + (size_t)wid * (NI / 4);
  float4 w[16];
#pragma unroll
  for (int j = 0; j < 16; ++j) w[j] = Wrow[j * 64 + lane];

  float mem = ws->cur0[wid];
  int my_fst = T_STEPS;

  for (int t = 1; t < T_STEPS; ++t) {
    const float4* xr = reinterpret_cast<const float4*>(x) + (size_t)t * (NI / 4);
    float acc = 0.0f;
#pragma unroll
    for (int j = 0; j < 16; ++j) {
      float4 xv = xr[j * 64 + lane];
      acc += xv.x * w[j].x + xv.y * w[j].y + xv.z * w[j].z + xv.w * w[j].w;
    }
#pragma unroll
    for (int off = 32; off >= 1; off >>= 1) acc += __shfl_xor(acc, off, 64);

    const float reset = (mem > THRESH) ? THRESH : 0.0f;
    mem = BETA * mem + acc - reset;

    if (lane == 0) mem_rec[(size_t)t * NO + wid] = mem;
    if (mem > THRESH) { my_fst = t; break; }
  }

  if (lane == 0) {
    ws->fst[wid] = my_fst;
    atomicMin(&ws->tstar, my_fst);
  }
}

// General-path winner candidates (fst[o] == tstar, 0 < tstar < T). Gated.
__global__ void k_fix(Ws* __restrict__ ws) {
  const int ts = ws->tstar;
  if (ts == 0 || ts >= T_STEPS) return;
  const int o = blockIdx.x * blockDim.x + threadIdx.x;
  if (o >= NO) return;
  if (ws->fst[o] == ts) atomicMax(&ws->packed, winner_key(ts, o));
}

// Epilogue: first half of the grid streams the spk region (zeros + winner
// one-hot); second half zeroes mem rows t > tstar. Row 0 (and 1..tstar on
// the general path) were written by k_gemv0 / k_slow.
__global__ __launch_bounds__(256) void k_out(float4* __restrict__ out,
                                             const Ws* __restrict__ ws) {
  const int ts = ws->tstar;
  const unsigned half = gridDim.x >> 1;
  const float4 z = {0.0f, 0.0f, 0.0f, 0.0f};

  if (blockIdx.x < half) {
    unsigned wflat = 0xFFFFFFFFu; // flat float index of winner in spk
    if (ts < T_STEPS) {
      const unsigned o =
          (unsigned)(NO - 1) - (unsigned)(ws->packed & 0xFFFFFFFFull);
      wflat = (unsigned)ts * (unsigned)NO + o;
    }
    const unsigned tid    = blockIdx.x * 256u + threadIdx.x;
    const unsigned stride = half * 256u;
    for (unsigned v = tid; v < SPK_VEC4; v += stride) {
      float4 val = z;
      const unsigned d = wflat - v * 4u; // unsigned wrap: only 0..3 hit
      if (d < 4u) reinterpret_cast<float*>(&val)[d] = 1.0f;
      out[v] = val;
    }
  } else {
    const unsigned base   = SPK_VEC4 + (unsigned)(ts + 1) * (NO / 4u);
    const unsigned tid    = (blockIdx.x - half) * 256u + threadIdx.x;
    const unsigned stride = (gridDim.x - half) * 256u;
    for (unsigned v = base + tid; v < TOT_VEC4; v += stride) out[v] = z;
  }
}

extern "C" void kernel_launch(void* const* d_in, const int* in_sizes, int n_in,
                              void* d_out, int out_size, void* d_ws, size_t ws_size,
                              hipStream_t stream) {
  const float* x = (const float*)d_in[0]; // [T, NI]
  const float* W = (const float*)d_in[1]; // [NO, NI]
  float* mem = (float*)d_out + (size_t)T_STEPS * NO;   // output 1: [T, NO]
  Ws* ws = (Ws*)d_ws;

  k_gemv0<<<NO, 256, 0, stream>>>(x, W, mem, ws);
  k_reduce0<<<1, 1024, 0, stream>>>(ws);
  k_slow<<<(NO * 64) / 256, 256, 0, stream>>>(x, W, mem, ws);
  k_fix<<<NO / 256, 256, 0, stream>>>(ws);
  k_out<<<4096, 256, 0, stream>>>((float4*)d_out, ws);
}

// Round 5
// 29.210 us; speedup vs baseline: 2.8881x; 1.8598x over previous
//
#include <hip/hip_runtime.h>

#define T_STEPS 2048
#define NI 4096
#define NO 4096

static constexpr float BETA = 0.9f;
static constexpr float THRESH = 1.0f;

#define SPK_FLOATS ((unsigned)T_STEPS * (unsigned)NO)      // 8,388,608
#define SPK_VEC4   (SPK_FLOATS / 4u)                       // 2,097,152
#define TOT_VEC4   (2u * SPK_VEC4)                         // 4,194,304
#define ZB         2048u                                   // zero blocks
#define Z4TOT      (TOT_VEC4 - 1024u)                      // skip mem row 0

// Workspace layout in d_ws
struct Ws {
  int tstar;                   // global first spike step
  int pad;
  unsigned long long packed;   // winner key (bit63 | mant<<32 | (NO-1-o))
  float cur0[NO];              // cur at t=0 (general-path restart)
  int fst[NO];                 // per-neuron first spike (general path)
  int wmax[NO];                // last mem row written (general path)
  unsigned long long key0[NO]; // t=0 winner keys (0 = not a spiker)
};

// ---- Threefry-2x32, key = (0, 42), matching JAX's threefry2x32 ----
__device__ inline void threefry2x32(unsigned k0, unsigned k1,
                                    unsigned& x0, unsigned& x1) {
  const unsigned k2 = k0 ^ k1 ^ 0x1BD11BDAu;
  x0 += k0; x1 += k1;
#define TF_RND(r) { x0 += x1; x1 = (x1 << (r)) | (x1 >> (32 - (r))); x1 ^= x0; }
  TF_RND(13) TF_RND(15) TF_RND(26) TF_RND(6)
  x0 += k1; x1 += k2 + 1u;
  TF_RND(17) TF_RND(29) TF_RND(16) TF_RND(24)
  x0 += k2; x1 += k0 + 2u;
  TF_RND(13) TF_RND(15) TF_RND(26) TF_RND(6)
  x0 += k0; x1 += k1 + 3u;
  TF_RND(17) TF_RND(29) TF_RND(16) TF_RND(24)
  x0 += k1; x1 += k2 + 4u;
  TF_RND(13) TF_RND(15) TF_RND(26) TF_RND(6)
  x0 += k2; x1 += k0 + 5u;
#undef TF_RND
}

// Winner key for neuron o spiking at step ts. Bit 63 marks "candidate";
// mant monotone in the uniform; low word breaks ties toward smaller o.
__device__ inline unsigned long long winner_key(int ts, int o) {
  const unsigned H = (unsigned)T_STEPS * (unsigned)NO / 2u; // 4194304
  const unsigned i = (unsigned)ts * (unsigned)NO + (unsigned)o;
  unsigned c0 = (i < H) ? i : (i - H);
  unsigned c1 = (i < H) ? (i + H) : i;
  threefry2x32(0u, 42u, c0, c1);
  const unsigned bits = (i < H) ? c0 : c1;
  const unsigned mant = bits >> 9;
  return (1ull << 63) | ((unsigned long long)mant << 32) |
         (unsigned)(NO - 1 - o);
}

// Fused: 4096 GEMV blocks (bid%3 != 2) compute cur0[o]=x[0]·W[o], write mem
// row 0 + per-neuron winner key (no atomics); 2048 zero blocks (bid%3 == 2)
// stream zeros over spk and mem rows 1..2047. Interleaved so read-bound and
// write-bound blocks share every CU and the HBM pipe concurrently.
__global__ __launch_bounds__(256) void k_main(const float* __restrict__ x,
                                              const float* __restrict__ W,
                                              float* __restrict__ out,
                                              Ws* __restrict__ ws) {
  const unsigned bid = blockIdx.x;
  const unsigned tid = threadIdx.x;
  const unsigned q   = bid / 3u;
  const unsigned r   = bid % 3u;

  if (r == 2u) {
    // ---- zero block q in [0, ZB) ----
    float4* o4 = reinterpret_cast<float4*>(out);
    const float4 z = {0.0f, 0.0f, 0.0f, 0.0f};
    const unsigned base = q * 2048u + tid;
#pragma unroll
    for (int k = 0; k < 8; ++k) {
      const unsigned j = base + (unsigned)k * 256u;
      if (j < Z4TOT) {
        const unsigned v = (j < SPK_VEC4) ? j : j + 1024u; // skip mem row 0
        o4[v] = z;
      }
    }
    return;
  }

  // ---- GEMV block: neuron o in [0, NO) ----
  const int o = (int)(q * 2u + r);
  const float4* Wrow = reinterpret_cast<const float4*>(W) + (size_t)o * (NI / 4);
  const float4* xr   = reinterpret_cast<const float4*>(x); // row 0

  float acc = 0.0f;
#pragma unroll
  for (int k = 0; k < 4; ++k) {
    const int idx = (int)tid + k * 256;
    float4 wv = Wrow[idx];
    float4 xv = xr[idx];
    acc += wv.x * xv.x + wv.y * xv.y + wv.z * xv.z + wv.w * xv.w;
  }
#pragma unroll
  for (int off = 32; off >= 1; off >>= 1) acc += __shfl_xor(acc, off, 64);

  __shared__ float part[4];
  if ((tid & 63u) == 0u) part[tid >> 6] = acc;
  __syncthreads();
  if (tid == 0u) {
    const float cur = part[0] + part[1] + part[2] + part[3];
    out[SPK_FLOATS + o] = cur;  // mem row 0 (always recorded; done starts False)
    ws->cur0[o] = cur;
    ws->key0[o] = (cur > THRESH) ? winner_key(0, o) : 0ull;
  }
}

// Single-block max-reduce over key0: sets tstar (0 if any t=0 spiker, else
// T_STEPS) and packed. No atomics on the fast path.
__global__ __launch_bounds__(1024) void k_finish(Ws* __restrict__ ws) {
  const int tid = (int)threadIdx.x;
  unsigned long long k = 0ull;
#pragma unroll
  for (int j = 0; j < NO / 1024; ++j) {
    const unsigned long long v = ws->key0[tid + j * 1024];
    k = (v > k) ? v : k;
  }
#pragma unroll
  for (int off = 32; off >= 1; off >>= 1) {
    const unsigned long long v = __shfl_xor(k, off, 64);
    k = (v > k) ? v : k;
  }
  __shared__ unsigned long long part[16];
  if ((tid & 63) == 0) part[tid >> 6] = k;
  __syncthreads();
  if (tid == 0) {
    unsigned long long m = 0ull;
#pragma unroll
    for (int j = 0; j < 16; ++j) m = (part[j] > m) ? part[j] : m;
    ws->packed = m;
    ws->tstar  = (m != 0ull) ? 0 : T_STEPS;
  }
}

// General-path fallback: only runs if NO neuron spiked at t=0 (never for the
// benchmark input — exits immediately). One wave per neuron from t=1; mem
// rows were pre-zeroed by k_main, overwritten here up to each neuron's fst.
__global__ __launch_bounds__(256) void k_slow(const float* __restrict__ x,
                                              const float* __restrict__ W,
                                              float* __restrict__ mem_rec,
                                              Ws* __restrict__ ws) {
  if (ws->tstar == 0) return;

  const int wid  = (int)((blockIdx.x * blockDim.x + threadIdx.x) >> 6);
  const int lane = (int)(threadIdx.x & 63);
  if (wid >= NO) return;

  const float4* Wrow = reinterpret_cast<const float4*>(W) + (size_t)wid * (NI / 4);
  float4 w[16];
#pragma unroll
  for (int j = 0; j < 16; ++j) w[j] = Wrow[j * 64 + lane];

  float mem = ws->cur0[wid];
  int my_fst = T_STEPS;
  int wmax = 0;

  for (int t = 1; t < T_STEPS; ++t) {
    const float4* xr = reinterpret_cast<const float4*>(x) + (size_t)t * (NI / 4);
    float acc = 0.0f;
#pragma unroll
    for (int j = 0; j < 16; ++j) {
      float4 xv = xr[j * 64 + lane];
      acc += xv.x * w[j].x + xv.y * w[j].y + xv.z * w[j].z + xv.w * w[j].w;
    }
#pragma unroll
    for (int off = 32; off >= 1; off >>= 1) acc += __shfl_xor(acc, off, 64);

    const float reset = (mem > THRESH) ? THRESH : 0.0f;
    mem = BETA * mem + acc - reset;

    if (lane == 0) mem_rec[(size_t)t * NO + wid] = mem;
    wmax = t;
    if (mem > THRESH) { my_fst = t; break; }
  }

  if (lane == 0) {
    ws->fst[wid] = my_fst;
    ws->wmax[wid] = wmax;
    atomicMin(&ws->tstar, my_fst);
  }
}

// General path only: re-zero overshoot rows (tstar, wmax] and gather winner
// candidates (fst[o] == tstar). Gated out on the fast path.
__global__ void k_fix(float* __restrict__ mem_rec, Ws* __restrict__ ws) {
  const int ts = ws->tstar;
  if (ts == 0 || ts >= T_STEPS) return;
  const int o = blockIdx.x * blockDim.x + threadIdx.x;
  if (o >= NO) return;
  const int wm = ws->wmax[o];
  for (int t = ts + 1; t <= wm; ++t)
    mem_rec[(size_t)t * NO + o] = 0.0f;
  if (ws->fst[o] == ts) atomicMax(&ws->packed, winner_key(ts, o));
}

// Write the winner one-hot (both paths; spk was zeroed by k_main).
__global__ void k_wwrite(float* __restrict__ spk_rec, Ws* __restrict__ ws) {
  const int ts = ws->tstar;
  if (ts < T_STEPS) {
    const unsigned o =
        (unsigned)(NO - 1) - (unsigned)(ws->packed & 0xFFFFFFFFull);
    spk_rec[(size_t)ts * NO + o] = 1.0f;
  }
}

extern "C" void kernel_launch(void* const* d_in, const int* in_sizes, int n_in,
                              void* d_out, int out_size, void* d_ws, size_t ws_size,
                              hipStream_t stream) {
  const float* x = (const float*)d_in[0]; // [T, NI]
  const float* W = (const float*)d_in[1]; // [NO, NI]
  float* spk = (float*)d_out;                          // output 0: [T, NO]
  float* mem = (float*)d_out + (size_t)SPK_FLOATS;     // output 1: [T, NO]
  Ws* ws = (Ws*)d_ws;

  k_main<<<NO + (int)ZB, 256, 0, stream>>>(x, W, (float*)d_out, ws);
  k_finish<<<1, 1024, 0, stream>>>(ws);
  k_slow<<<(NO * 64) / 256, 256, 0, stream>>>(x, W, mem, ws);
  k_fix<<<NO / 256, 256, 0, stream>>>(mem, ws);
  k_wwrite<<<1, 1, 0, stream>>>(spk, ws);
}

// Round 6
// 27.875 us; speedup vs baseline: 3.0264x; 1.0479x over previous
//
#include <hip/hip_runtime.h>

#define T_STEPS 2048
#define NI 4096
#define NO 4096

static constexpr float BETA = 0.9f;
static constexpr float THRESH = 1.0f;

#define SPK_FLOATS ((unsigned)T_STEPS * (unsigned)NO)      // 8,388,608
#define SPK_VEC4   (SPK_FLOATS / 4u)                       // 2,097,152
#define TOT_VEC4   (2u * SPK_VEC4)                         // 4,194,304
#define ZB         2048u                                   // zero blocks
#define Z4TOT      (TOT_VEC4 - 1024u)                      // skip mem row 0

typedef float f4 __attribute__((ext_vector_type(4)));

// Workspace layout in d_ws
struct Ws {
  int tstar;                   // 0 = fast path taken; T_STEPS = general path
  int pad;
  float cur0[NO];              // cur at t=0 (general-path restart)
  int fst[NO];                 // per-neuron first spike (general path)
  int wmax[NO];                // last mem row written (general path)
  unsigned long long key0[NO]; // t=0 winner keys (0 = not a spiker)
  unsigned long long keyG[NO]; // general-path keys: (T-fst, mant, NO-1-o)
};

// ---- Threefry-2x32, key = (0, 42), matching JAX's threefry2x32 ----
__device__ inline void threefry2x32(unsigned k0, unsigned k1,
                                    unsigned& x0, unsigned& x1) {
  const unsigned k2 = k0 ^ k1 ^ 0x1BD11BDAu;
  x0 += k0; x1 += k1;
#define TF_RND(r) { x0 += x1; x1 = (x1 << (r)) | (x1 >> (32 - (r))); x1 ^= x0; }
  TF_RND(13) TF_RND(15) TF_RND(26) TF_RND(6)
  x0 += k1; x1 += k2 + 1u;
  TF_RND(17) TF_RND(29) TF_RND(16) TF_RND(24)
  x0 += k2; x1 += k0 + 2u;
  TF_RND(13) TF_RND(15) TF_RND(26) TF_RND(6)
  x0 += k0; x1 += k1 + 3u;
  TF_RND(17) TF_RND(29) TF_RND(16) TF_RND(24)
  x0 += k1; x1 += k2 + 4u;
  TF_RND(13) TF_RND(15) TF_RND(26) TF_RND(6)
  x0 += k2; x1 += k0 + 5u;
#undef TF_RND
}

// Noise mantissa bits (monotone in the uniform float) at (ts, o).
__device__ inline unsigned noise_mant(int ts, int o) {
  const unsigned H = (unsigned)T_STEPS * (unsigned)NO / 2u; // 4194304
  const unsigned i = (unsigned)ts * (unsigned)NO + (unsigned)o;
  unsigned c0 = (i < H) ? i : (i - H);
  unsigned c1 = (i < H) ? (i + H) : i;
  threefry2x32(0u, 42u, c0, c1);
  return ((i < H) ? c0 : c1) >> 9; // 23 bits
}

// Fused: 4096 GEMV blocks (bid%3 != 2) compute cur0[o]=x[0]·W[o], write mem
// row 0 + per-neuron t=0 winner key (no atomics); 2048 zero blocks (bid%3==2)
// stream zeros (non-temporal) over spk and mem rows 1..2047. Interleaved so
// read-bound and write-bound blocks share every CU / the HBM pipe.
__global__ __launch_bounds__(256) void k_main(const float* __restrict__ x,
                                              const float* __restrict__ W,
                                              float* __restrict__ out,
                                              Ws* __restrict__ ws) {
  const unsigned bid = blockIdx.x;
  const unsigned tid = threadIdx.x;
  const unsigned q   = bid / 3u;
  const unsigned r   = bid % 3u;

  if (r == 2u) {
    // ---- zero block q in [0, ZB) ----
    f4* o4 = reinterpret_cast<f4*>(out);
    const f4 z = {0.0f, 0.0f, 0.0f, 0.0f};
    const unsigned base = q * 2048u + tid;
#pragma unroll
    for (int k = 0; k < 8; ++k) {
      const unsigned j = base + (unsigned)k * 256u;
      if (j < Z4TOT) {
        const unsigned v = (j < SPK_VEC4) ? j : j + 1024u; // skip mem row 0
        __builtin_nontemporal_store(z, &o4[v]);
      }
    }
    return;
  }

  // ---- GEMV block: neuron o in [0, NO) ----
  const int o = (int)(q * 2u + r);
  const float4* Wrow = reinterpret_cast<const float4*>(W) + (size_t)o * (NI / 4);
  const float4* xr   = reinterpret_cast<const float4*>(x); // row 0

  float acc = 0.0f;
#pragma unroll
  for (int k = 0; k < 4; ++k) {
    const int idx = (int)tid + k * 256;
    float4 wv = Wrow[idx];
    float4 xv = xr[idx];
    acc += wv.x * xv.x + wv.y * xv.y + wv.z * xv.z + wv.w * xv.w;
  }
#pragma unroll
  for (int off = 32; off >= 1; off >>= 1) acc += __shfl_xor(acc, off, 64);

  __shared__ float part[4];
  if ((tid & 63u) == 0u) part[tid >> 6] = acc;
  __syncthreads();
  if (tid == 0u) {
    const float cur = part[0] + part[1] + part[2] + part[3];
    out[SPK_FLOATS + o] = cur;  // mem row 0 (always recorded; done starts False)
    ws->cur0[o] = cur;
    ws->key0[o] = (cur > THRESH)
        ? ((1ull << 63) | ((unsigned long long)noise_mant(0, o) << 32) |
           (unsigned)(NO - 1 - o))
        : 0ull;
  }
}

// Fast-path finish: single-block max-reduce over key0. If any t=0 spiker,
// tstar=0 and the winner one-hot is written here (spk zeros landed in
// k_main — cross-dispatch ordering). No atomics anywhere on the fast path.
__global__ __launch_bounds__(1024) void k_finish(float* __restrict__ spk,
                                                 Ws* __restrict__ ws) {
  const int tid = (int)threadIdx.x;
  unsigned long long k = 0ull;
#pragma unroll
  for (int j = 0; j < NO / 1024; ++j) {
    const unsigned long long v = ws->key0[tid + j * 1024];
    k = (v > k) ? v : k;
  }
#pragma unroll
  for (int off = 32; off >= 1; off >>= 1) {
    const unsigned long long v = __shfl_xor(k, off, 64);
    k = (v > k) ? v : k;
  }
  __shared__ unsigned long long part[16];
  if ((tid & 63) == 0) part[tid >> 6] = k;
  __syncthreads();
  if (tid == 0) {
    unsigned long long m = 0ull;
#pragma unroll
    for (int j = 0; j < 16; ++j) m = (part[j] > m) ? part[j] : m;
    if (m != 0ull) {
      ws->tstar = 0;
      const unsigned o = (unsigned)(NO - 1) - (unsigned)(m & 0xFFFFFFFFull);
      spk[o] = 1.0f; // row 0
    } else {
      ws->tstar = T_STEPS;
    }
  }
}

// General-path fallback: only runs if NO neuron spiked at t=0 (never for the
// benchmark input — exits immediately). One wave per neuron from t=1; mem
// rows were pre-zeroed by k_main, overwritten here up to each neuron's fst.
// Packs (T-fst, noise mant at fst, NO-1-o) into keyG for a single reduce.
__global__ __launch_bounds__(256) void k_slow(const float* __restrict__ x,
                                              const float* __restrict__ W,
                                              float* __restrict__ mem_rec,
                                              Ws* __restrict__ ws) {
  if (ws->tstar == 0) return;

  const int wid  = (int)((blockIdx.x * blockDim.x + threadIdx.x) >> 6);
  const int lane = (int)(threadIdx.x & 63);
  if (wid >= NO) return;

  const float4* Wrow = reinterpret_cast<const float4*>(W) + (size_t)wid * (NI / 4);
  float4 w[16];
#pragma unroll
  for (int j = 0; j < 16; ++j) w[j] = Wrow[j * 64 + lane];

  float mem = ws->cur0[wid];
  int my_fst = T_STEPS;
  int wmax = 0;

  for (int t = 1; t < T_STEPS; ++t) {
    const float4* xr = reinterpret_cast<const float4*>(x) + (size_t)t * (NI / 4);
    float acc = 0.0f;
#pragma unroll
    for (int j = 0; j < 16; ++j) {
      float4 xv = xr[j * 64 + lane];
      acc += xv.x * w[j].x + xv.y * w[j].y + xv.z * w[j].z + xv.w * w[j].w;
    }
#pragma unroll
    for (int off = 32; off >= 1; off >>= 1) acc += __shfl_xor(acc, off, 64);

    const float reset = (mem > THRESH) ? THRESH : 0.0f;
    mem = BETA * mem + acc - reset;

    if (lane == 0) mem_rec[(size_t)t * NO + wid] = mem;
    wmax = t;
    if (mem > THRESH) { my_fst = t; break; }
  }

  if (lane == 0) {
    ws->fst[wid]  = my_fst;
    ws->wmax[wid] = wmax;
    // bits [35:46] = T-fst (min fst wins), [12:34] = mant (max noise wins),
    // [0:11] = NO-1-o (smaller o wins ties). fst==T -> top field 0.
    const unsigned mant = (my_fst < T_STEPS) ? noise_mant(my_fst, wid) : 0u;
    ws->keyG[wid] =
        ((unsigned long long)(unsigned)(T_STEPS - my_fst) << 35) |
        ((unsigned long long)mant << 12) |
        (unsigned)(NO - 1 - wid);
  }
}

// General-path finish (gated): reduce keyG -> tstar/winner, write one-hot,
// re-zero overshoot rows (tstar, wmax[o]]. Performance-irrelevant (never
// runs on the benchmark input) but keeps the kernel semantically general.
__global__ __launch_bounds__(1024) void k_gfin(float* __restrict__ spk,
                                               float* __restrict__ mem_rec,
                                               Ws* __restrict__ ws) {
  if (ws->tstar == 0) return; // fast path already finished

  const int tid = (int)threadIdx.x;
  unsigned long long k = 0ull;
#pragma unroll
  for (int j = 0; j < NO / 1024; ++j) {
    const unsigned long long v = ws->keyG[tid + j * 1024];
    k = (v > k) ? v : k;
  }
#pragma unroll
  for (int off = 32; off >= 1; off >>= 1) {
    const unsigned long long v = __shfl_xor(k, off, 64);
    k = (v > k) ? v : k;
  }
  __shared__ unsigned long long part[16];
  __shared__ int s_ts;
  if ((tid & 63) == 0) part[tid >> 6] = k;
  __syncthreads();
  if (tid == 0) {
    unsigned long long m = 0ull;
#pragma unroll
    for (int j = 0; j < 16; ++j) m = (part[j] > m) ? part[j] : m;
    const int ts = T_STEPS - (int)((m >> 35) & 0xFFFull);
    s_ts = ts;
    if (ts < T_STEPS) {
      const unsigned o = (unsigned)(NO - 1) - (unsigned)(m & 0xFFFull);
      spk[(size_t)ts * NO + o] = 1.0f;
    }
    ws->tstar = ts;
  }
  __syncthreads();
  const int ts = s_ts;
  if (ts >= T_STEPS) return;
  for (int o = tid; o < NO; o += 1024) {
    const int wm = ws->wmax[o];
    for (int t = ts + 1; t <= wm; ++t)
      mem_rec[(size_t)t * NO + o] = 0.0f;
  }
}

extern "C" void kernel_launch(void* const* d_in, const int* in_sizes, int n_in,
                              void* d_out, int out_size, void* d_ws, size_t ws_size,
                              hipStream_t stream) {
  const float* x = (const float*)d_in[0]; // [T, NI]
  const float* W = (const float*)d_in[1]; // [NO, NI]
  float* spk = (float*)d_out;                          // output 0: [T, NO]
  float* mem = (float*)d_out + (size_t)SPK_FLOATS;     // output 1: [T, NO]
  Ws* ws = (Ws*)d_ws;

  k_main<<<NO + (int)ZB, 256, 0, stream>>>(x, W, (float*)d_out, ws);
  k_finish<<<1, 1024, 0, stream>>>(spk, ws);
  k_slow<<<(NO * 64) / 256, 256, 0, stream>>>(x, W, mem, ws);
  k_gfin<<<1, 1024, 0, stream>>>(spk, mem, ws);
}

// Round 7
// 25.912 us; speedup vs baseline: 3.2557x; 1.0758x over previous
//
#include <hip/hip_runtime.h>

#define T_STEPS 2048
#define NI 4096
#define NO 4096

static constexpr float BETA = 0.9f;
static constexpr float THRESH = 1.0f;

#define SPK_FLOATS ((unsigned)T_STEPS * (unsigned)NO)      // 8,388,608
#define SPK_VEC4   (SPK_FLOATS / 4u)                       // 2,097,152
#define TOT_VEC4   (2u * SPK_VEC4)                         // 4,194,304
#define ZB         2048u                                   // zero blocks
#define Z4TOT      (TOT_VEC4 - 1024u)                      // skip mem row 0

typedef float f4 __attribute__((ext_vector_type(4)));

// Workspace: just cur0. Fully rewritten every call (no stale-state reliance).
struct Ws {
  float cur0[NO]; // cur at t=0 = x[0]·W[o]
};

// ---- Threefry-2x32, key = (0, 42), matching JAX's threefry2x32 ----
__device__ inline void threefry2x32(unsigned k0, unsigned k1,
                                    unsigned& x0, unsigned& x1) {
  const unsigned k2 = k0 ^ k1 ^ 0x1BD11BDAu;
  x0 += k0; x1 += k1;
#define TF_RND(r) { x0 += x1; x1 = (x1 << (r)) | (x1 >> (32 - (r))); x1 ^= x0; }
  TF_RND(13) TF_RND(15) TF_RND(26) TF_RND(6)
  x0 += k1; x1 += k2 + 1u;
  TF_RND(17) TF_RND(29) TF_RND(16) TF_RND(24)
  x0 += k2; x1 += k0 + 2u;
  TF_RND(13) TF_RND(15) TF_RND(26) TF_RND(6)
  x0 += k0; x1 += k1 + 3u;
  TF_RND(17) TF_RND(29) TF_RND(16) TF_RND(24)
  x0 += k1; x1 += k2 + 4u;
  TF_RND(13) TF_RND(15) TF_RND(26) TF_RND(6)
  x0 += k2; x1 += k0 + 5u;
#undef TF_RND
}

// Winner key for neuron o spiking at step ts: bit63 marks "candidate";
// bits[32:54] = noise mantissa (monotone in the uniform float);
// low word = NO-1-o (ties break toward smaller o, matching argmax).
__device__ inline unsigned long long winner_key(int ts, int o) {
  const unsigned H = (unsigned)T_STEPS * (unsigned)NO / 2u; // 4194304
  const unsigned i = (unsigned)ts * (unsigned)NO + (unsigned)o;
  unsigned c0 = (i < H) ? i : (i - H);
  unsigned c1 = (i < H) ? (i + H) : i;
  threefry2x32(0u, 42u, c0, c1);
  const unsigned mant = (((i < H) ? c0 : c1) >> 9); // 23 bits
  return (1ull << 63) | ((unsigned long long)mant << 32) |
         (unsigned)(NO - 1 - o);
}

// Block-wide (1024-thread) max-reduce with broadcast. `part` is 16-entry LDS.
__device__ inline unsigned long long
block_max_u64(unsigned long long k, unsigned long long* part) {
  const int tid = (int)threadIdx.x;
#pragma unroll
  for (int off = 32; off >= 1; off >>= 1) {
    const unsigned long long v = __shfl_xor(k, off, 64);
    k = (v > k) ? v : k;
  }
  if ((tid & 63) == 0) part[tid >> 6] = k;
  __syncthreads();
  if (tid == 0) {
    unsigned long long m = 0ull;
#pragma unroll
    for (int j = 0; j < 16; ++j) m = (part[j] > m) ? part[j] : m;
    part[0] = m;
  }
  __syncthreads();
  const unsigned long long m = part[0];
  __syncthreads(); // safe LDS reuse by caller
  return m;
}

// Fused main: 4096 GEMV blocks (bid%3 != 2) compute cur0[o] = x[0]·W[o] and
// write mem row 0 (always recorded — done starts False); 2048 zero blocks
// (bid%3 == 2) stream non-temporal zeros over spk and mem rows 1..2047.
// Interleaved so read-bound and write-bound blocks share every CU and the
// HBM pipe from the start. No atomics.
__global__ __launch_bounds__(256) void k_main(const float* __restrict__ x,
                                              const float* __restrict__ W,
                                              float* __restrict__ out,
                                              Ws* __restrict__ ws) {
  const unsigned bid = blockIdx.x;
  const unsigned tid = threadIdx.x;
  const unsigned q   = bid / 3u;
  const unsigned r   = bid % 3u;

  if (r == 2u) {
    // ---- zero block q in [0, ZB) ----
    f4* o4 = reinterpret_cast<f4*>(out);
    const f4 z = {0.0f, 0.0f, 0.0f, 0.0f};
    const unsigned base = q * 2048u + tid;
#pragma unroll
    for (int k = 0; k < 8; ++k) {
      const unsigned j = base + (unsigned)k * 256u;
      if (j < Z4TOT) {
        const unsigned v = (j < SPK_VEC4) ? j : j + 1024u; // skip mem row 0
        __builtin_nontemporal_store(z, &o4[v]);
      }
    }
    return;
  }

  // ---- GEMV block: neuron o in [0, NO) ----
  const int o = (int)(q * 2u + r);
  const float4* Wrow = reinterpret_cast<const float4*>(W) + (size_t)o * (NI / 4);
  const float4* xr   = reinterpret_cast<const float4*>(x); // row 0

  float acc = 0.0f;
#pragma unroll
  for (int k = 0; k < 4; ++k) {
    const int idx = (int)tid + k * 256;
    float4 wv = Wrow[idx];
    float4 xv = xr[idx];
    acc += wv.x * xv.x + wv.y * xv.y + wv.z * xv.z + wv.w * xv.w;
  }
#pragma unroll
  for (int off = 32; off >= 1; off >>= 1) acc += __shfl_xor(acc, off, 64);

  __shared__ float part[4];
  if ((tid & 63u) == 0u) part[tid >> 6] = acc;
  __syncthreads();
  if (tid == 0u) {
    const float cur = part[0] + part[1] + part[2] + part[3];
    out[SPK_FLOATS + o] = cur; // mem row 0
    ws->cur0[o] = cur;
  }
}

// Finish, single block of 1024 threads (4 neurons/thread).
// Fast path: reduce t=0 spiker keys from cur0, write winner one-hot, return.
// General path (gated; never runs on this input): exact in-block emulation of
// the reference scan from t=1 — x row staged in LDS, per-thread dots, mem row
// recorded BEFORE the spike check (matching the reference's record-then-done
// order), block-wide winner reduce, break at the first spiking step. Rows
// past the break stay zero (pre-zeroed by k_main).
__global__ __launch_bounds__(1024) void k_fin(const float* __restrict__ x,
                                              const float* __restrict__ W,
                                              float* __restrict__ spk,
                                              float* __restrict__ mem_rec,
                                              Ws* __restrict__ ws) {
  const int tid = (int)threadIdx.x;
  __shared__ unsigned long long part[16];
  __shared__ float xs[NI];

  float mem[4];
  unsigned long long k = 0ull;
#pragma unroll
  for (int j = 0; j < 4; ++j) {
    const int o = tid + j * 1024;
    const float c = ws->cur0[o];
    mem[j] = c;
    if (c > THRESH) {
      const unsigned long long v = winner_key(0, o);
      k = (v > k) ? v : k;
    }
  }
  unsigned long long m = block_max_u64(k, part);
  if (m != 0ull) { // fast path: spike at t=0
    if (tid == 0) {
      const unsigned o = (unsigned)(NO - 1) - (unsigned)(m & 0xFFFFFFFFull);
      spk[o] = 1.0f; // row 0
    }
    return;
  }

  // ---- general path (correctness-only; performance-irrelevant) ----
  for (int t = 1; t < T_STEPS; ++t) {
    for (int i = tid; i < NI; i += 1024) xs[i] = x[(size_t)t * NI + i];
    __syncthreads();

    unsigned long long kk = 0ull;
#pragma unroll
    for (int j = 0; j < 4; ++j) {
      const int o = tid + j * 1024;
      const float* Wrow = W + (size_t)o * NI;
      float acc = 0.0f;
      for (int i = 0; i < NI; ++i) acc += xs[i] * Wrow[i];
      const float reset = (mem[j] > THRESH) ? THRESH : 0.0f;
      mem[j] = BETA * mem[j] + acc - reset;
      mem_rec[(size_t)t * NO + o] = mem[j]; // recorded before done-check
      if (mem[j] > THRESH) {
        const unsigned long long v = winner_key(t, o);
        kk = (v > kk) ? v : kk;
      }
    }
    __syncthreads(); // xs reuse barrier
    m = block_max_u64(kk, part);
    if (m != 0ull) { // first spiking step: winner, then done -> zeros remain
      if (tid == 0) {
        const unsigned o = (unsigned)(NO - 1) - (unsigned)(m & 0xFFFFFFFFull);
        spk[(size_t)t * NO + o] = 1.0f;
      }
      return;
    }
  }
}

extern "C" void kernel_launch(void* const* d_in, const int* in_sizes, int n_in,
                              void* d_out, int out_size, void* d_ws, size_t ws_size,
                              hipStream_t stream) {
  const float* x = (const float*)d_in[0]; // [T, NI]
  const float* W = (const float*)d_in[1]; // [NO, NI]
  float* spk = (float*)d_out;                          // output 0: [T, NO]
  float* mem = (float*)d_out + (size_t)SPK_FLOATS;     // output 1: [T, NO]
  Ws* ws = (Ws*)d_ws;

  k_main<<<NO + (int)ZB, 256, 0, stream>>>(x, W, (float*)d_out, ws);
  k_fin<<<1, 1024, 0, stream>>>(x, W, spk, mem, ws);
}